// Round 1
// baseline (1450.118 us; speedup 1.0000x reference)
//
#include <hip/hip_runtime.h>
#include <hip/hip_bf16.h>
#include <math.h>

#define H 128
#define RPB 32        // rows per node_update block
#define LDSTRIDE 132  // H + 4 pad, keeps float4 alignment, breaks bank aliasing

// ---------------- prep: transpose weights, sigmoid(ew), zero counters ----------------
__global__ void prep_kernel(const float* __restrict__ ew,
                            const float* __restrict__ W_d2e,
                            const float* __restrict__ W_e_self,
                            const float* __restrict__ W_e2d,
                            const float* __restrict__ W_d_self,
                            float* __restrict__ sigw,
                            int* __restrict__ cnt1, int* __restrict__ cnt2,
                            float* __restrict__ WTd2e, float* __restrict__ WTes,
                            float* __restrict__ WTe2d, float* __restrict__ WTds,
                            int N_e, int N_d) {
    int i = blockIdx.x * blockDim.x + threadIdx.x;
    if (i < H * H) {
        int h = i >> 7, o = i & (H - 1);
        int src = o * H + h;           // WT[h][o] = W[o][h]
        WTd2e[i] = W_d2e[src];
        WTes[i]  = W_e_self[src];
        WTe2d[i] = W_e2d[src];
        WTds[i]  = W_d_self[src];
    }
    if (i < N_e) { sigw[i] = 1.0f / (1.0f + expf(-ew[i])); cnt1[i] = 0; }
    if (i < N_d) { cnt2[i] = 0; }
}

// ---------------- CSR build ----------------
__global__ void hist_kernel(const int* __restrict__ e_d2e, const int* __restrict__ e_e2d,
                            int* __restrict__ cnt1, int* __restrict__ cnt2, int E) {
    int e = blockIdx.x * blockDim.x + threadIdx.x;
    if (e < E) {
        atomicAdd(&cnt1[e_d2e[E + e]], 1);   // row1 = e_dst
        atomicAdd(&cnt2[e_e2d[E + e]], 1);   // row1 = d_dst
    }
}

__global__ void scan_kernel(const int* __restrict__ cnt1, int* __restrict__ off1,
                            int* __restrict__ cur1, int N1,
                            const int* __restrict__ cnt2, int* __restrict__ off2,
                            int* __restrict__ cur2, int N2) {
    const int* cnt = blockIdx.x ? cnt2 : cnt1;
    int* off = blockIdx.x ? off2 : off1;
    int* cur = blockIdx.x ? cur2 : cur1;
    int N    = blockIdx.x ? N2 : N1;
    __shared__ int part[257];
    int tid = threadIdx.x;
    int chunk = (N + 255) / 256;
    int lo = tid * chunk, hi = min(lo + chunk, N);
    int s = 0;
    for (int i = lo; i < hi; ++i) s += cnt[i];
    part[tid] = s;
    __syncthreads();
    if (tid == 0) {
        int run = 0;
        for (int i = 0; i < 256; ++i) { int t = part[i]; part[i] = run; run += t; }
        part[256] = run;
    }
    __syncthreads();
    int run = part[tid];
    for (int i = lo; i < hi; ++i) { off[i] = run; cur[i] = run; run += cnt[i]; }
    if (tid == 0) off[N] = part[256];
}

__global__ void fill_kernel(const int* __restrict__ e_d2e, const int* __restrict__ e_e2d,
                            int* __restrict__ cur1, int* __restrict__ srcs1,
                            int* __restrict__ cur2, int* __restrict__ srcs2, int E) {
    int e = blockIdx.x * blockDim.x + threadIdx.x;
    if (e < E) {
        int p1 = atomicAdd(&cur1[e_d2e[E + e]], 1); srcs1[p1] = e_d2e[e];
        int p2 = atomicAdd(&cur2[e_e2d[E + e]], 1); srcs2[p2] = e_e2d[e];
    }
}

// ---------------- fused node update: gather-sum + 2 matvecs + bias/ReLU/residual/LN ----------------
// rows = b*Nn + n.  Wave w handles 8 rows; lane holds outputs o=lane and o=lane+64.
__global__ __launch_bounds__(256, 4)
void node_update_kernel(const float* __restrict__ x,
                        const float* __restrict__ gsrc,
                        const int* __restrict__ off,
                        const int* __restrict__ srcs,
                        const float* __restrict__ sigw,     // null for phase D
                        const float* __restrict__ WTself,
                        const float* __restrict__ WTmsg,
                        const float* __restrict__ bias,
                        const float* __restrict__ gamma,
                        const float* __restrict__ beta,
                        float* __restrict__ out,
                        int Nn, int Ng, int nrows) {
    __shared__ __align__(16) float x_lds[RPB * LDSTRIDE];
    __shared__ __align__(16) float S_lds[RPB * LDSTRIDE];

    const int tid  = threadIdx.x;
    const int row0 = blockIdx.x * RPB;

    // ---- stage x rows and scaled gather-sums into LDS ----
    {
        int lh = tid & (H - 1);   // 0..127
        int rhalf = tid >> 7;     // 0 or 1
        for (int r = rhalf; r < RPB; r += 2) {
            int rg = row0 + r;
            float xv = 0.f, sv = 0.f;
            if (rg < nrows) {
                int n = rg % Nn;
                int b = rg / Nn;
                xv = x[(size_t)rg * H + lh];
                int beg = off[n], end = off[n + 1];
                const float* gbase = gsrc + (size_t)b * Ng * H;
                for (int j = beg; j < end; ++j)
                    sv += gbase[(size_t)srcs[j] * H + lh];
                float deg = (float)(end - beg);
                float scale = (sigw ? sigw[n] : 1.0f) / fmaxf(deg, 1.0f);
                sv *= scale;
            }
            x_lds[r * LDSTRIDE + lh] = xv;
            S_lds[r * LDSTRIDE + lh] = sv;
        }
    }
    __syncthreads();

    const int wave  = tid >> 6;
    const int lane  = tid & 63;
    const int o0 = lane, o1 = lane + 64;
    const int rbase = wave * 8;

    float acc0[8], acc1[8];
#pragma unroll
    for (int r = 0; r < 8; ++r) { acc0[r] = 0.f; acc1[r] = 0.f; }

    // self matvec: acc[r][o] += sum_h x[r][h] * WTself[h][o]
    for (int h = 0; h < H; h += 4) {
        float w00 = WTself[(h + 0) * H + o0], w01 = WTself[(h + 0) * H + o1];
        float w10 = WTself[(h + 1) * H + o0], w11 = WTself[(h + 1) * H + o1];
        float w20 = WTself[(h + 2) * H + o0], w21 = WTself[(h + 2) * H + o1];
        float w30 = WTself[(h + 3) * H + o0], w31 = WTself[(h + 3) * H + o1];
#pragma unroll
        for (int r = 0; r < 8; ++r) {
            const float4 xv = *reinterpret_cast<const float4*>(&x_lds[(rbase + r) * LDSTRIDE + h]);
            acc0[r] += xv.x * w00 + xv.y * w10 + xv.z * w20 + xv.w * w30;
            acc1[r] += xv.x * w01 + xv.y * w11 + xv.z * w21 + xv.w * w31;
        }
    }

    // msg matvec — skip if every row of this wave has degree 0 (S rows all zero)
    bool any = false;
#pragma unroll
    for (int r = 0; r < 8; ++r) {
        int rg = row0 + rbase + r;
        if (rg < nrows) {
            int n = rg % Nn;
            if (off[n + 1] > off[n]) any = true;
        }
    }
    if (any) {
        for (int h = 0; h < H; h += 4) {
            float w00 = WTmsg[(h + 0) * H + o0], w01 = WTmsg[(h + 0) * H + o1];
            float w10 = WTmsg[(h + 1) * H + o0], w11 = WTmsg[(h + 1) * H + o1];
            float w20 = WTmsg[(h + 2) * H + o0], w21 = WTmsg[(h + 2) * H + o1];
            float w30 = WTmsg[(h + 3) * H + o0], w31 = WTmsg[(h + 3) * H + o1];
#pragma unroll
            for (int r = 0; r < 8; ++r) {
                const float4 sv = *reinterpret_cast<const float4*>(&S_lds[(rbase + r) * LDSTRIDE + h]);
                acc0[r] += sv.x * w00 + sv.y * w10 + sv.z * w20 + sv.w * w30;
                acc1[r] += sv.x * w01 + sv.y * w11 + sv.z * w21 + sv.w * w31;
            }
        }
    }

    // ---- epilogue: bias, ReLU, residual, LayerNorm (in-wave shuffle), store ----
    const float g0 = gamma[o0], g1 = gamma[o1];
    const float be0 = beta[o0], be1 = beta[o1];
    const float bb0 = bias[o0], bb1 = bias[o1];
    for (int r = 0; r < 8; ++r) {
        int rg = row0 + rbase + r;       // wave-uniform
        if (rg >= nrows) break;
        float x0 = x_lds[(rbase + r) * LDSTRIDE + o0];
        float x1 = x_lds[(rbase + r) * LDSTRIDE + o1];
        float p0 = fmaxf(acc0[r] + bb0, 0.f);
        float p1 = fmaxf(acc1[r] + bb1, 0.f);
        float xn0 = x0 + p0, xn1 = x1 + p1;
        float s  = xn0 + xn1;
        float s2 = xn0 * xn0 + xn1 * xn1;
#pragma unroll
        for (int m = 32; m >= 1; m >>= 1) {
            s  += __shfl_xor(s, m, 64);
            s2 += __shfl_xor(s2, m, 64);
        }
        float mean = s * (1.0f / H);
        float var  = s2 * (1.0f / H) - mean * mean;
        float rstd = rsqrtf(var + 1e-5f);
        out[(size_t)rg * H + o0] = (xn0 - mean) * rstd * g0 + be0;
        out[(size_t)rg * H + o1] = (xn1 - mean) * rstd * g1 + be1;
    }
}

extern "C" void kernel_launch(void* const* d_in, const int* in_sizes, int n_in,
                              void* d_out, int out_size, void* d_ws, size_t ws_size,
                              hipStream_t stream) {
    const float* hD       = (const float*)d_in[0];
    const float* hE       = (const float*)d_in[1];
    const int*   e_d2e    = (const int*)d_in[2];
    const int*   e_e2d    = (const int*)d_in[3];
    const float* ew       = (const float*)d_in[4];
    const float* W_d2e    = (const float*)d_in[5];
    const float* W_e_self = (const float*)d_in[6];
    const float* b_e      = (const float*)d_in[7];
    const float* g_e      = (const float*)d_in[8];
    const float* beta_e   = (const float*)d_in[9];
    const float* W_e2d    = (const float*)d_in[10];
    const float* W_d_self = (const float*)d_in[11];
    const float* b_d      = (const float*)d_in[12];
    const float* g_d      = (const float*)d_in[13];
    const float* beta_d   = (const float*)d_in[14];

    const int E   = in_sizes[2] / 2;
    const int N_e = in_sizes[4];
    const int Bsz = in_sizes[1] / (N_e * H);
    const int N_d = in_sizes[0] / (Bsz * H);

    float* outD = (float*)d_out;                           // hD_new, return order first
    float* outE = (float*)d_out + (size_t)Bsz * N_d * H;   // hE_new

    // workspace carve (256B aligned)
    char* p = (char*)d_ws;
    auto alloc = [&](size_t bytes) { char* r = p; p += (bytes + 255) & ~(size_t)255; return r; };
    int*   cnt1  = (int*)alloc((size_t)N_e * 4);
    int*   off1  = (int*)alloc((size_t)(N_e + 1) * 4);
    int*   cur1  = (int*)alloc((size_t)N_e * 4);
    int*   srcs1 = (int*)alloc((size_t)E * 4);
    int*   cnt2  = (int*)alloc((size_t)N_d * 4);
    int*   off2  = (int*)alloc((size_t)(N_d + 1) * 4);
    int*   cur2  = (int*)alloc((size_t)N_d * 4);
    int*   srcs2 = (int*)alloc((size_t)E * 4);
    float* sigw  = (float*)alloc((size_t)N_e * 4);
    float* WTd2e = (float*)alloc((size_t)H * H * 4);
    float* WTes  = (float*)alloc((size_t)H * H * 4);
    float* WTe2d = (float*)alloc((size_t)H * H * 4);
    float* WTds  = (float*)alloc((size_t)H * H * 4);

    int prepN = H * H;
    if (N_e > prepN) prepN = N_e;
    if (N_d > prepN) prepN = N_d;
    prep_kernel<<<(prepN + 255) / 256, 256, 0, stream>>>(
        ew, W_d2e, W_e_self, W_e2d, W_d_self,
        sigw, cnt1, cnt2, WTd2e, WTes, WTe2d, WTds, N_e, N_d);
    hist_kernel<<<(E + 255) / 256, 256, 0, stream>>>(e_d2e, e_e2d, cnt1, cnt2, E);
    scan_kernel<<<2, 256, 0, stream>>>(cnt1, off1, cur1, N_e, cnt2, off2, cur2, N_d);
    fill_kernel<<<(E + 255) / 256, 256, 0, stream>>>(e_d2e, e_e2d, cur1, srcs1, cur2, srcs2, E);

    // Phase B: E-node update (gathers hD via CSR1, sigmoid weights)
    int rowsB = Bsz * N_e;
    node_update_kernel<<<(rowsB + RPB - 1) / RPB, 256, 0, stream>>>(
        hE, hD, off1, srcs1, sigw, WTes, WTd2e, b_e, g_e, beta_e, outE, N_e, N_d, rowsB);

    // Phase D: D-node update (gathers hE_new from d_out via CSR2)
    int rowsD = Bsz * N_d;
    node_update_kernel<<<(rowsD + RPB - 1) / RPB, 256, 0, stream>>>(
        hD, outE, off2, srcs2, nullptr, WTds, WTe2d, b_d, g_d, beta_d, outD, N_d, N_e, rowsD);
}

// Round 2
// 1291.833 us; speedup vs baseline: 1.1225x; 1.1225x over previous
//
#include <hip/hip_runtime.h>
#include <math.h>

#define H 128
#define ROWS 64          // rows per node_update block
#define ASTRIDE 264      // bf16 elems per row in Abuf (256 + 8 pad -> 2-way-free LDS banks)
#define XSTRIDE 132      // fp32 elems per row in aliased XN view (264*2B == 132*4B)

typedef __attribute__((ext_vector_type(8))) short short8;
typedef __attribute__((ext_vector_type(4))) float floatx4;

__device__ __forceinline__ unsigned short f2bf(float f) {
    unsigned int u = __float_as_uint(f);
    u += 0x7FFFu + ((u >> 16) & 1u);       // round-to-nearest-even
    return (unsigned short)(u >> 16);
}

// ---------------- prep: sigmoid(ew), zero counters ----------------
__global__ void prep_kernel(const float* __restrict__ ew, float* __restrict__ sigw,
                            int* __restrict__ cnt1, int* __restrict__ cnt2,
                            int N_e, int N_d) {
    int i = blockIdx.x * blockDim.x + threadIdx.x;
    if (i < N_e) { sigw[i] = 1.0f / (1.0f + expf(-ew[i])); cnt1[i] = 0; }
    if (i < N_d) cnt2[i] = 0;
}

// ---------------- prep: bf16 B-operand fragments for MFMA ----------------
// Bfrag[t][kk][lane][j] = Wcat[k = kk*32 + (lane>>4)*8 + j][n = t*16 + (lane&15)]
// where Wcat[k][n] = (k<128 ? Wself[n][k] : Wmsg[n][k-128])   (y = x @ W.T)
__global__ void wfrag_kernel(const float* __restrict__ Wself,
                             const float* __restrict__ Wmsg,
                             unsigned short* __restrict__ Bfrag) {
    int idx = blockIdx.x * blockDim.x + threadIdx.x;   // 0..32767
    int j    = idx & 7;
    int lane = (idx >> 3) & 63;
    int kk   = (idx >> 9) & 7;
    int t    = idx >> 12;
    int k = kk * 32 + ((lane >> 4) << 3) + j;
    int n = (t << 4) + (lane & 15);
    float w = (k < H) ? Wself[n * H + k] : Wmsg[n * H + (k - H)];
    Bfrag[idx] = f2bf(w);
}

// ---------------- CSR build ----------------
__global__ void hist_kernel(const int* __restrict__ e_d2e, const int* __restrict__ e_e2d,
                            int* __restrict__ cnt1, int* __restrict__ cnt2, int E) {
    int e = blockIdx.x * blockDim.x + threadIdx.x;
    if (e < E) {
        atomicAdd(&cnt1[e_d2e[E + e]], 1);
        atomicAdd(&cnt2[e_e2d[E + e]], 1);
    }
}

__global__ void scan_kernel(const int* __restrict__ cnt1, int* __restrict__ off1,
                            int* __restrict__ cur1, int N1,
                            const int* __restrict__ cnt2, int* __restrict__ off2,
                            int* __restrict__ cur2, int N2) {
    const int* cnt = blockIdx.x ? cnt2 : cnt1;
    int* off = blockIdx.x ? off2 : off1;
    int* cur = blockIdx.x ? cur2 : cur1;
    int N    = blockIdx.x ? N2 : N1;
    __shared__ int part[257];
    int tid = threadIdx.x;
    int chunk = (N + 255) / 256;
    int lo = tid * chunk, hi = min(lo + chunk, N);
    int s = 0;
    for (int i = lo; i < hi; ++i) s += cnt[i];
    part[tid] = s;
    __syncthreads();
    if (tid == 0) {
        int run = 0;
        for (int i = 0; i < 256; ++i) { int t = part[i]; part[i] = run; run += t; }
        part[256] = run;
    }
    __syncthreads();
    int run = part[tid];
    for (int i = lo; i < hi; ++i) { off[i] = run; cur[i] = run; run += cnt[i]; }
    if (tid == 0) off[N] = part[256];
}

__global__ void fill_kernel(const int* __restrict__ e_d2e, const int* __restrict__ e_e2d,
                            int* __restrict__ cur1, int* __restrict__ srcs1,
                            int* __restrict__ cur2, int* __restrict__ srcs2, int E) {
    int e = blockIdx.x * blockDim.x + threadIdx.x;
    if (e < E) {
        int p1 = atomicAdd(&cur1[e_d2e[E + e]], 1); srcs1[p1] = e_d2e[e];
        int p2 = atomicAdd(&cur2[e_e2d[E + e]], 1); srcs2[p2] = e_e2d[e];
    }
}

// ---------------- fused node update (MFMA version) ----------------
// Block: 64 rows x 128 outputs. Single GEMM [64 x 256(K)] @ [256 x 128]
// with A = [x_bf16 | S_bf16] and B = [Wself^T; Wmsg^T] (pre-fragmentized).
// Wave w owns n-tiles {2w, 2w+1} (cols 32w..32w+31), all 4 m-tiles.
__global__ __launch_bounds__(256, 4)
void node_update_kernel(const float* __restrict__ x,
                        const float* __restrict__ gsrc,
                        const int* __restrict__ off,
                        const int* __restrict__ srcs,
                        const float* __restrict__ sigw,     // null for phase D
                        const unsigned short* __restrict__ Bfrag,
                        const float* __restrict__ bias,
                        const float* __restrict__ gamma,
                        const float* __restrict__ beta,
                        float* __restrict__ out,
                        int nShift, int nMask, long gStride, int nrows) {
    __shared__ __align__(16) unsigned short Abuf[ROWS * ASTRIDE];
    float* XN = reinterpret_cast<float*>(Abuf);   // aliased: reused after MFMA

    const int tid  = threadIdx.x;
    const int row0 = blockIdx.x * ROWS;

    // ---- stage: x -> bf16, scaled gather-sum -> bf16 ----
    {
        int lh = tid & (H - 1);
        for (int r = tid >> 7; r < ROWS; r += 2) {
            int rg = row0 + r;
            float xv = 0.f, sv = 0.f;
            if (rg < nrows) {
                int n = rg & nMask;
                int b = rg >> nShift;
                xv = x[(size_t)rg * H + lh];
                int beg = off[n], end = off[n + 1];
                const float* gbase = gsrc + (size_t)b * gStride;
                for (int jj = beg; jj < end; ++jj)
                    sv += gbase[(size_t)srcs[jj] * H + lh];
                float scale = (sigw ? sigw[n] : 1.0f) / fmaxf((float)(end - beg), 1.0f);
                sv *= scale;
            }
            Abuf[r * ASTRIDE + lh]     = f2bf(xv);
            Abuf[r * ASTRIDE + H + lh] = f2bf(sv);
        }
    }
    __syncthreads();

    const int wave = tid >> 6, lane = tid & 63;
    const int quad = lane >> 4, l16 = lane & 15;

    floatx4 acc[4][2];
#pragma unroll
    for (int mt = 0; mt < 4; ++mt)
#pragma unroll
        for (int t = 0; t < 2; ++t)
            acc[mt][t] = (floatx4){0.f, 0.f, 0.f, 0.f};

    // ---- MFMA main loop: K = 256 in 8 chunks of 32 ----
    const unsigned short* bf_base = Bfrag + (size_t)(2 * wave) * 4096;  // t stride = 8*64*8
    for (int kk = 0; kk < 8; ++kk) {
        const short8 b0 = *reinterpret_cast<const short8*>(bf_base + (kk * 64 + lane) * 8);
        const short8 b1 = *reinterpret_cast<const short8*>(bf_base + 4096 + (kk * 64 + lane) * 8);
#pragma unroll
        for (int mt = 0; mt < 4; ++mt) {
            const short8 a = *reinterpret_cast<const short8*>(
                &Abuf[(16 * mt + l16) * ASTRIDE + kk * 32 + quad * 8]);
            acc[mt][0] = __builtin_amdgcn_mfma_f32_16x16x32_bf16(a, b0, acc[mt][0], 0, 0, 0);
            acc[mt][1] = __builtin_amdgcn_mfma_f32_16x16x32_bf16(a, b1, acc[mt][1], 0, 0, 0);
        }
    }
    __syncthreads();   // all Abuf reads complete before XN overwrite

    // ---- epilogue 1: bias + ReLU + fp32 residual (re-read x, L1/L2-hot) -> XN ----
#pragma unroll
    for (int t = 0; t < 2; ++t) {
        int col = 32 * wave + 16 * t + l16;
        float bb = bias[col];
#pragma unroll
        for (int mt = 0; mt < 4; ++mt) {
#pragma unroll
            for (int reg = 0; reg < 4; ++reg) {
                int r  = 16 * mt + quad * 4 + reg;   // C/D: row = quad*4+reg, col = lane&15
                int rg = row0 + r;
                float pre = fmaxf(acc[mt][t][reg] + bb, 0.f);
                float xn  = (rg < nrows ? x[(size_t)rg * H + col] : 0.f) + pre;
                XN[r * XSTRIDE + col] = xn;
            }
        }
    }
    __syncthreads();

    // ---- epilogue 2: LayerNorm (wave handles 16 rows; lane -> cols {lane, lane+64}) ----
    {
        const int o0 = lane, o1 = lane + 64;
        const float g0 = gamma[o0], g1 = gamma[o1];
        const float be0 = beta[o0], be1 = beta[o1];
        for (int rr = 0; rr < 16; ++rr) {
            int r  = 16 * wave + rr;
            int rg = row0 + r;
            if (rg >= nrows) break;
            float xn0 = XN[r * XSTRIDE + o0];
            float xn1 = XN[r * XSTRIDE + o1];
            float s  = xn0 + xn1;
            float s2 = xn0 * xn0 + xn1 * xn1;
#pragma unroll
            for (int m = 32; m >= 1; m >>= 1) {
                s  += __shfl_xor(s, m, 64);
                s2 += __shfl_xor(s2, m, 64);
            }
            float mean = s * (1.0f / H);
            float var  = s2 * (1.0f / H) - mean * mean;
            float rstd = rsqrtf(var + 1e-5f);
            out[(size_t)rg * H + o0] = (xn0 - mean) * rstd * g0 + be0;
            out[(size_t)rg * H + o1] = (xn1 - mean) * rstd * g1 + be1;
        }
    }
}

extern "C" void kernel_launch(void* const* d_in, const int* in_sizes, int n_in,
                              void* d_out, int out_size, void* d_ws, size_t ws_size,
                              hipStream_t stream) {
    const float* hD       = (const float*)d_in[0];
    const float* hE       = (const float*)d_in[1];
    const int*   e_d2e    = (const int*)d_in[2];
    const int*   e_e2d    = (const int*)d_in[3];
    const float* ew       = (const float*)d_in[4];
    const float* W_d2e    = (const float*)d_in[5];
    const float* W_e_self = (const float*)d_in[6];
    const float* b_e      = (const float*)d_in[7];
    const float* g_e      = (const float*)d_in[8];
    const float* beta_e   = (const float*)d_in[9];
    const float* W_e2d    = (const float*)d_in[10];
    const float* W_d_self = (const float*)d_in[11];
    const float* b_d      = (const float*)d_in[12];
    const float* g_d      = (const float*)d_in[13];
    const float* beta_d   = (const float*)d_in[14];

    const int E   = in_sizes[2] / 2;
    const int N_e = in_sizes[4];
    const int Bsz = in_sizes[1] / (N_e * H);
    const int N_d = in_sizes[0] / (Bsz * H);

    float* outD = (float*)d_out;
    float* outE = (float*)d_out + (size_t)Bsz * N_d * H;

    char* p = (char*)d_ws;
    auto alloc = [&](size_t bytes) { char* r = p; p += (bytes + 255) & ~(size_t)255; return r; };
    int*   cnt1   = (int*)alloc((size_t)N_e * 4);
    int*   off1   = (int*)alloc((size_t)(N_e + 1) * 4);
    int*   cur1   = (int*)alloc((size_t)N_e * 4);
    int*   srcs1  = (int*)alloc((size_t)E * 4);
    int*   cnt2   = (int*)alloc((size_t)N_d * 4);
    int*   off2   = (int*)alloc((size_t)(N_d + 1) * 4);
    int*   cur2   = (int*)alloc((size_t)N_d * 4);
    int*   srcs2  = (int*)alloc((size_t)E * 4);
    float* sigw   = (float*)alloc((size_t)N_e * 4);
    unsigned short* BfragB = (unsigned short*)alloc((size_t)32768 * 2);  // phase B weights
    unsigned short* BfragD = (unsigned short*)alloc((size_t)32768 * 2);  // phase D weights

    int prepN = (N_e > N_d) ? N_e : N_d;
    prep_kernel<<<(prepN + 255) / 256, 256, 0, stream>>>(ew, sigw, cnt1, cnt2, N_e, N_d);
    wfrag_kernel<<<128, 256, 0, stream>>>(W_e_self, W_d2e, BfragB);
    wfrag_kernel<<<128, 256, 0, stream>>>(W_d_self, W_e2d, BfragD);
    hist_kernel<<<(E + 255) / 256, 256, 0, stream>>>(e_d2e, e_e2d, cnt1, cnt2, E);
    scan_kernel<<<2, 256, 0, stream>>>(cnt1, off1, cur1, N_e, cnt2, off2, cur2, N_d);
    fill_kernel<<<(E + 255) / 256, 256, 0, stream>>>(e_d2e, e_e2d, cur1, srcs1, cur2, srcs2, E);

    // Phase B: E-node update (gathers hD via CSR1, sigmoid weights)
    int rowsB = Bsz * N_e;
    int shB = __builtin_ctz(N_e);
    node_update_kernel<<<(rowsB + ROWS - 1) / ROWS, 256, 0, stream>>>(
        hE, hD, off1, srcs1, sigw, BfragB, b_e, g_e, beta_e, outE,
        shB, N_e - 1, (long)N_d * H, rowsB);

    // Phase D: D-node update (gathers hE_new from d_out via CSR2)
    int rowsD = Bsz * N_d;
    int shD = __builtin_ctz(N_d);
    node_update_kernel<<<(rowsD + ROWS - 1) / ROWS, 256, 0, stream>>>(
        hD, outE, off2, srcs2, nullptr, BfragD, b_d, g_d, beta_d, outD,
        shD, N_d - 1, (long)N_e * H, rowsD);
}

// Round 3
// 701.426 us; speedup vs baseline: 2.0674x; 1.8417x over previous
//
#include <hip/hip_runtime.h>
#include <math.h>

#define H 128
#define ROWS 32          // rows per node_update block (32 consecutive n, one b)
#define ASTRIDE 264      // bf16 elems per row in Abuf (256 + 8 pad)
#define XSTRIDE 132      // fp32 elems per row in aliased XN view (264*2B == 132*4B)
#define IDXCAP 1024      // LDS-staged CSR srcs per block (avg 128/256; global fallback past cap)

typedef __attribute__((ext_vector_type(8))) short short8;
typedef __attribute__((ext_vector_type(4))) float floatx4;

__device__ __forceinline__ unsigned short f2bf(float f) {
    unsigned int u = __float_as_uint(f);
    u += 0x7FFFu + ((u >> 16) & 1u);       // round-to-nearest-even
    return (unsigned short)(u >> 16);
}

// ---------------- prep: sigmoid(ew), zero counters ----------------
__global__ void prep_kernel(const float* __restrict__ ew, float* __restrict__ sigw,
                            int* __restrict__ cnt1, int* __restrict__ cnt2,
                            int N_e, int N_d) {
    int i = blockIdx.x * blockDim.x + threadIdx.x;
    if (i < N_e) { sigw[i] = 1.0f / (1.0f + expf(-ew[i])); cnt1[i] = 0; }
    if (i < N_d) cnt2[i] = 0;
}

// ---------------- prep: bf16 B-operand fragments for MFMA ----------------
// Bfrag[t][kk][lane][j] = Wcat[k = kk*32 + (lane>>4)*8 + j][n = t*16 + (lane&15)]
// where Wcat[k][n] = (k<128 ? Wself[n][k] : Wmsg[n][k-128])   (y = x @ W.T)
__global__ void wfrag_kernel(const float* __restrict__ Wself,
                             const float* __restrict__ Wmsg,
                             unsigned short* __restrict__ Bfrag) {
    int idx = blockIdx.x * blockDim.x + threadIdx.x;   // 0..32767
    int j    = idx & 7;
    int lane = (idx >> 3) & 63;
    int kk   = (idx >> 9) & 7;
    int t    = idx >> 12;
    int k = kk * 32 + ((lane >> 4) << 3) + j;
    int n = (t << 4) + (lane & 15);
    float w = (k < H) ? Wself[n * H + k] : Wmsg[n * H + (k - H)];
    Bfrag[idx] = f2bf(w);
}

// ---------------- CSR build ----------------
__global__ void hist_kernel(const int* __restrict__ e_d2e, const int* __restrict__ e_e2d,
                            int* __restrict__ cnt1, int* __restrict__ cnt2, int E) {
    int e = blockIdx.x * blockDim.x + threadIdx.x;
    if (e < E) {
        atomicAdd(&cnt1[e_d2e[E + e]], 1);
        atomicAdd(&cnt2[e_e2d[E + e]], 1);
    }
}

__global__ void scan_kernel(const int* __restrict__ cnt1, int* __restrict__ off1,
                            int* __restrict__ cur1, int N1,
                            const int* __restrict__ cnt2, int* __restrict__ off2,
                            int* __restrict__ cur2, int N2) {
    const int* cnt = blockIdx.x ? cnt2 : cnt1;
    int* off = blockIdx.x ? off2 : off1;
    int* cur = blockIdx.x ? cur2 : cur1;
    int N    = blockIdx.x ? N2 : N1;
    __shared__ int part[257];
    int tid = threadIdx.x;
    int chunk = (N + 255) / 256;
    int lo = tid * chunk, hi = min(lo + chunk, N);
    int s = 0;
    for (int i = lo; i < hi; ++i) s += cnt[i];
    part[tid] = s;
    __syncthreads();
    if (tid == 0) {
        int run = 0;
        for (int i = 0; i < 256; ++i) { int t = part[i]; part[i] = run; run += t; }
        part[256] = run;
    }
    __syncthreads();
    int run = part[tid];
    for (int i = lo; i < hi; ++i) { off[i] = run; cur[i] = run; run += cnt[i]; }
    if (tid == 0) off[N] = part[256];
}

__global__ void fill_kernel(const int* __restrict__ e_d2e, const int* __restrict__ e_e2d,
                            int* __restrict__ cur1, int* __restrict__ srcs1,
                            int* __restrict__ cur2, int* __restrict__ srcs2, int E) {
    int e = blockIdx.x * blockDim.x + threadIdx.x;
    if (e < E) {
        int p1 = atomicAdd(&cur1[e_d2e[E + e]], 1); srcs1[p1] = e_d2e[e];
        int p2 = atomicAdd(&cur2[e_e2d[E + e]], 1); srcs2[p2] = e_e2d[e];
    }
}

// ---------------- fused node update (MFMA + LDS-staged CSR) ----------------
// Block: 32 rows x 128 outputs. GEMM [32 x 256(K)] @ [256 x 128],
// A = [x_bf16 | S_bf16], B = [Wself^T; Wmsg^T] pre-fragmentized.
// Wave w owns n-tiles {2w, 2w+1}; m-tiles 0..1.
__global__ __launch_bounds__(256, 7)
void node_update_kernel(const float* __restrict__ x,
                        const float* __restrict__ gsrc,
                        const int* __restrict__ off,
                        const int* __restrict__ srcs,
                        const float* __restrict__ sigw,     // null for phase D
                        const unsigned short* __restrict__ Bfrag,
                        const float* __restrict__ bias,
                        const float* __restrict__ gamma,
                        const float* __restrict__ beta,
                        float* __restrict__ out,
                        int nShift, int nMask, long gStride, int nrows) {
    __shared__ __align__(16) unsigned short Abuf[ROWS * ASTRIDE];
    __shared__ int idxbuf[IDXCAP];
    __shared__ int offs[ROWS + 1];
    float* XN = reinterpret_cast<float*>(Abuf);   // aliased: reused after MFMA

    const int tid  = threadIdx.x;
    const int row0 = blockIdx.x * ROWS;
    const int n0   = row0 & nMask;     // rows are 32 consecutive n of one b (N % 32 == 0)

    // ---- stage CSR offsets + source indices into LDS ----
    if (tid <= ROWS) offs[tid] = off[n0 + tid];
    __syncthreads();
    const int jbase = offs[0];
    const int jlds  = min(offs[ROWS] - jbase, IDXCAP);
    for (int j = tid; j < jlds; j += 256) idxbuf[j] = srcs[jbase + j];
    __syncthreads();

    // ---- stage: x -> bf16, scaled gather-sum -> bf16 (4 gathers in flight) ----
    {
        const int lh = tid & (H - 1);
        const int rh = tid >> 7;
        const float* gb = gsrc + (size_t)(row0 >> nShift) * gStride;
        for (int r = rh; r < ROWS; r += 2) {
            int rg = row0 + r;
            float xv = 0.f, sv = 0.f;
            if (rg < nrows) {
                xv = x[(size_t)rg * H + lh];
                int beg = offs[r] - jbase, end = offs[r + 1] - jbase;
                int j = beg;
                for (; j + 4 <= end; j += 4) {
                    int s0 = (j + 0 < IDXCAP) ? idxbuf[j + 0] : srcs[jbase + j + 0];
                    int s1 = (j + 1 < IDXCAP) ? idxbuf[j + 1] : srcs[jbase + j + 1];
                    int s2 = (j + 2 < IDXCAP) ? idxbuf[j + 2] : srcs[jbase + j + 2];
                    int s3 = (j + 3 < IDXCAP) ? idxbuf[j + 3] : srcs[jbase + j + 3];
                    float v0 = gb[(size_t)s0 * H + lh];
                    float v1 = gb[(size_t)s1 * H + lh];
                    float v2 = gb[(size_t)s2 * H + lh];
                    float v3 = gb[(size_t)s3 * H + lh];
                    sv += (v0 + v1) + (v2 + v3);
                }
                for (; j < end; ++j) {
                    int s = (j < IDXCAP) ? idxbuf[j] : srcs[jbase + j];
                    sv += gb[(size_t)s * H + lh];
                }
                float scale = (sigw ? sigw[n0 + r] : 1.0f) / fmaxf((float)(end - beg), 1.0f);
                sv *= scale;
            }
            Abuf[r * ASTRIDE + lh]     = f2bf(xv);
            Abuf[r * ASTRIDE + H + lh] = f2bf(sv);
        }
    }
    __syncthreads();

    const int wave = tid >> 6, lane = tid & 63;
    const int quad = lane >> 4, l16 = lane & 15;

    floatx4 acc[2][2];
#pragma unroll
    for (int mt = 0; mt < 2; ++mt)
#pragma unroll
        for (int t = 0; t < 2; ++t)
            acc[mt][t] = (floatx4){0.f, 0.f, 0.f, 0.f};

    // ---- MFMA main loop: K = 256 in 8 chunks of 32 ----
    const unsigned short* bf_base = Bfrag + (size_t)(2 * wave) * 4096;  // t stride = 8*64*8
    for (int kk = 0; kk < 8; ++kk) {
        const short8 b0 = *reinterpret_cast<const short8*>(bf_base + (kk * 64 + lane) * 8);
        const short8 b1 = *reinterpret_cast<const short8*>(bf_base + 4096 + (kk * 64 + lane) * 8);
#pragma unroll
        for (int mt = 0; mt < 2; ++mt) {
            const short8 a = *reinterpret_cast<const short8*>(
                &Abuf[(16 * mt + l16) * ASTRIDE + kk * 32 + quad * 8]);
            acc[mt][0] = __builtin_amdgcn_mfma_f32_16x16x32_bf16(a, b0, acc[mt][0], 0, 0, 0);
            acc[mt][1] = __builtin_amdgcn_mfma_f32_16x16x32_bf16(a, b1, acc[mt][1], 0, 0, 0);
        }
    }
    __syncthreads();   // all Abuf reads complete before XN overwrite

    // ---- epilogue 1: bias + ReLU + fp32 residual (re-read x, L2-hot) -> XN ----
#pragma unroll
    for (int t = 0; t < 2; ++t) {
        int col = 32 * wave + 16 * t + l16;
        float bb = bias[col];
#pragma unroll
        for (int mt = 0; mt < 2; ++mt) {
#pragma unroll
            for (int reg = 0; reg < 4; ++reg) {
                int r  = 16 * mt + quad * 4 + reg;   // C/D: row = quad*4+reg, col = lane&15
                int rg = row0 + r;
                float pre = fmaxf(acc[mt][t][reg] + bb, 0.f);
                float xn  = (rg < nrows ? x[(size_t)rg * H + col] : 0.f) + pre;
                XN[r * XSTRIDE + col] = xn;
            }
        }
    }
    __syncthreads();

    // ---- epilogue 2: LayerNorm (wave handles 8 rows; lane -> cols {lane, lane+64}) ----
    {
        const int o0 = lane, o1 = lane + 64;
        const float g0 = gamma[o0], g1 = gamma[o1];
        const float be0 = beta[o0], be1 = beta[o1];
        for (int rr = 0; rr < 8; ++rr) {
            int r  = 8 * wave + rr;
            int rg = row0 + r;
            if (rg >= nrows) break;
            float xn0 = XN[r * XSTRIDE + o0];
            float xn1 = XN[r * XSTRIDE + o1];
            float s  = xn0 + xn1;
            float s2 = xn0 * xn0 + xn1 * xn1;
#pragma unroll
            for (int m = 32; m >= 1; m >>= 1) {
                s  += __shfl_xor(s, m, 64);
                s2 += __shfl_xor(s2, m, 64);
            }
            float mean = s * (1.0f / H);
            float var  = s2 * (1.0f / H) - mean * mean;
            float rstd = rsqrtf(var + 1e-5f);
            out[(size_t)rg * H + o0] = (xn0 - mean) * rstd * g0 + be0;
            out[(size_t)rg * H + o1] = (xn1 - mean) * rstd * g1 + be1;
        }
    }
}

extern "C" void kernel_launch(void* const* d_in, const int* in_sizes, int n_in,
                              void* d_out, int out_size, void* d_ws, size_t ws_size,
                              hipStream_t stream) {
    const float* hD       = (const float*)d_in[0];
    const float* hE       = (const float*)d_in[1];
    const int*   e_d2e    = (const int*)d_in[2];
    const int*   e_e2d    = (const int*)d_in[3];
    const float* ew       = (const float*)d_in[4];
    const float* W_d2e    = (const float*)d_in[5];
    const float* W_e_self = (const float*)d_in[6];
    const float* b_e      = (const float*)d_in[7];
    const float* g_e      = (const float*)d_in[8];
    const float* beta_e   = (const float*)d_in[9];
    const float* W_e2d    = (const float*)d_in[10];
    const float* W_d_self = (const float*)d_in[11];
    const float* b_d      = (const float*)d_in[12];
    const float* g_d      = (const float*)d_in[13];
    const float* beta_d   = (const float*)d_in[14];

    const int E   = in_sizes[2] / 2;
    const int N_e = in_sizes[4];
    const int Bsz = in_sizes[1] / (N_e * H);
    const int N_d = in_sizes[0] / (Bsz * H);

    float* outD = (float*)d_out;
    float* outE = (float*)d_out + (size_t)Bsz * N_d * H;

    char* p = (char*)d_ws;
    auto alloc = [&](size_t bytes) { char* r = p; p += (bytes + 255) & ~(size_t)255; return r; };
    int*   cnt1   = (int*)alloc((size_t)N_e * 4);
    int*   off1   = (int*)alloc((size_t)(N_e + 1) * 4);
    int*   cur1   = (int*)alloc((size_t)N_e * 4);
    int*   srcs1  = (int*)alloc((size_t)E * 4);
    int*   cnt2   = (int*)alloc((size_t)N_d * 4);
    int*   off2   = (int*)alloc((size_t)(N_d + 1) * 4);
    int*   cur2   = (int*)alloc((size_t)N_d * 4);
    int*   srcs2  = (int*)alloc((size_t)E * 4);
    float* sigw   = (float*)alloc((size_t)N_e * 4);
    unsigned short* BfragB = (unsigned short*)alloc((size_t)32768 * 2);  // phase B weights
    unsigned short* BfragD = (unsigned short*)alloc((size_t)32768 * 2);  // phase D weights

    int prepN = (N_e > N_d) ? N_e : N_d;
    prep_kernel<<<(prepN + 255) / 256, 256, 0, stream>>>(ew, sigw, cnt1, cnt2, N_e, N_d);
    wfrag_kernel<<<128, 256, 0, stream>>>(W_e_self, W_d2e, BfragB);
    wfrag_kernel<<<128, 256, 0, stream>>>(W_d_self, W_e2d, BfragD);
    hist_kernel<<<(E + 255) / 256, 256, 0, stream>>>(e_d2e, e_e2d, cnt1, cnt2, E);
    scan_kernel<<<2, 256, 0, stream>>>(cnt1, off1, cur1, N_e, cnt2, off2, cur2, N_d);
    fill_kernel<<<(E + 255) / 256, 256, 0, stream>>>(e_d2e, e_e2d, cur1, srcs1, cur2, srcs2, E);

    // Phase B: E-node update (gathers hD via CSR1, sigmoid weights)
    int rowsB = Bsz * N_e;
    int shB = __builtin_ctz(N_e);
    node_update_kernel<<<(rowsB + ROWS - 1) / ROWS, 256, 0, stream>>>(
        hE, hD, off1, srcs1, sigw, BfragB, b_e, g_e, beta_e, outE,
        shB, N_e - 1, (long)N_d * H, rowsB);

    // Phase D: D-node update (gathers hE_new from d_out via CSR2)
    int rowsD = Bsz * N_d;
    int shD = __builtin_ctz(N_d);
    node_update_kernel<<<(rowsD + ROWS - 1) / ROWS, 256, 0, stream>>>(
        hD, outE, off2, srcs2, nullptr, BfragD, b_d, g_d, beta_d, outD,
        shD, N_d - 1, (long)N_e * H, rowsD);
}